// Round 14
// baseline (81.629 us; speedup 1.0000x reference)
//
#include <hip/hip_runtime.h>
#include <math.h>

// DSS layer, fully fused chunked state-space + MFMA (R14 = R13 resubmitted;
// R13 hit a GPU-acquisition timeout, no data).
// Per channel h (one block, 256 thr = 4 waves):
//   0a) powers z_n^0..32 -> LDS pre/pim[32][33]; c_n -> LDS   (no atomics)
//   A)  S = Zf @ U per 16-chunk tile (MFMA, hi/lo bf16 3-term)
//   0b) K[e] = sum_n Re(c_n z_n^e) (shfl-tree, overlaps A's MFMA tail)
//   B)  64-chunk Kogge-Stone carry scan; carries written BACK INTO SL
//       (saves CarL's 17.4 KB -> 34.9 KB total -> 4 blocks/CU resident)
//   C)  y = T@U + Rre@CarRe + Rni@CarIm (MFMA) -> YL staging
//   E)  y = D*u + YL, coalesced
// R12 post-mortem: kernel was latency-bound (VALUBusy 24%, occupancy 22%,
// 3 blocks/CU resident vs grid's 4, 589k LDS conflicts from CarL layout).
// This rev = residency + conflict + barrier-stage fixes; numerics identical.

static constexpr int kH = 1024;
static constexpr int kL = 2048;
static constexpr int kN = 32;
static constexpr float kEps = 1e-7f;

typedef __attribute__((ext_vector_type(8))) short s8;   // 8 bf16 (A/B frag)
typedef __attribute__((ext_vector_type(4))) float f4;   // C/D frag

__device__ __forceinline__ unsigned short f2bf(float x) {
    union { float f; unsigned u; } v; v.f = x;
    return (unsigned short)((v.u + 0x7fffu + ((v.u >> 16) & 1u)) >> 16);
}
__device__ __forceinline__ float bf2f(unsigned short b) {
    union { unsigned u; float f; } v; v.u = ((unsigned)b) << 16; return v.f;
}

#define MFMA __builtin_amdgcn_mfma_f32_16x16x32_bf16

__global__ __launch_bounds__(256)
void dss_fused(const float* __restrict__ u,
               const float* __restrict__ W,
               const float* __restrict__ Lam,
               const float* __restrict__ logstep,
               const float* __restrict__ Dv,
               float* __restrict__ y) {
    __shared__ float pre[kN][33];     // Re z^e, e=0..32
    __shared__ float pim[kN][33];     // Im z^e
    __shared__ float ccs[kN][2];      // c_n
    __shared__ float Kk[kN];          // K[e]
    __shared__ float SL[64][66];      // S exchange -> carry exchange (reused)
    __shared__ float YL[64][34];      // y staging
    // total ~= 34.9 KB -> 4 blocks/CU

    const int h = blockIdx.x;
    const int tid = threadIdx.x;
    const int wv = tid >> 6, lane = tid & 63;
    const int cl = lane & 15, hq = lane >> 4;
    const int c = 16 * wv + cl;       // this lane's chunk (stages A/C)

    // ---- u loads issued FIRST: HBM latency hides under 0a transcendentals
    const float* ug = u + (size_t)h * kL;
    const f4 ua0 = *(const f4*)(ug + 32*c + 8*hq);
    const f4 ua1 = *(const f4*)(ug + 32*c + 8*hq + 4);

    // ---------- 0a: z-powers and c_n ----------
    {
        const int n = tid >> 3, g = tid & 7;   // 32 modes x 8 power-groups
        const float step = expf(logstep[h]);
        const float lr = Lam[2*n], li = Lam[2*n+1];
        const float ar = step * lr, ai = step * li;
        const float ea = expf(ar);
        float sb, cb; sincosf(ai, &sb, &cb);
        const float zr = ea * cb, zi = ea * sb;
        const float t2r = fmaf(zr, zr, -zi*zi), t2i = 2.f*zr*zi;       // z^2
        const float z4r = fmaf(t2r, t2r, -t2i*t2i), z4i = 2.f*t2r*t2i; // z^4
        float qr = 1.f, qi = 0.f, br = z4r, bi = z4i;                  // (z^4)^g
#pragma unroll
        for (int b = 0; b < 3; ++b) {
            if ((g >> b) & 1) {
                const float t = fmaf(qr, br, -qi*bi);
                qi = fmaf(qr, bi, qi*br); qr = t;
            }
            const float t = fmaf(br, br, -bi*bi);
            bi = 2.f*br*bi; br = t;
        }
        float cr_ = qr, ci_ = qi;                 // z^{4g}
        pre[n][4*g] = cr_; pim[n][4*g] = ci_;
#pragma unroll
        for (int t = 1; t < 4; ++t) {
            const float nr2 = fmaf(cr_, zr, -ci_*zi);
            ci_ = fmaf(cr_, zi, ci_*zr); cr_ = nr2;
            pre[n][4*g+t] = cr_; pim[n][4*g+t] = ci_;
        }
        if (g == 7) {                             // z^32
            const float nr2 = fmaf(cr_, zr, -ci_*zi);
            ci_ = fmaf(cr_, zi, ci_*zr); cr_ = nr2;
            pre[n][32] = cr_; pim[n][32] = ci_;
        }
        if (g == 0) {                             // c_n closed form
            const float wr = W[((size_t)h*kN+n)*2], wi = W[((size_t)h*kN+n)*2+1];
            const float em = expm1f(ar);
            const float sh = sinf(0.5f*ai);
            const float dr = fmaf(-em, cb, 2.f*sh*sh), di = -ea*sb;  // 1-z safe
            const float eL = expf(ar*(float)kL);
            float sL, cL2; sincosf(ai*(float)kL, &sL, &cL2);
            const float nrr = 1.f - eL*cL2, nii = -eL*sL;            // 1-z^L
            const float dd = dr*dr + di*di, id = 1.f/dd;
            const float srr = (nrr*dr + nii*di)*id, sii = (nii*dr - nrr*di)*id;
            const float ll = lr*lr + li*li, il = 1.f/ll;
            const float qrr = (wr*lr + wi*li)*il, qii = (wi*lr - wr*li)*il;
            const float ssq = fmaf(srr, srr, fmaf(sii, sii, kEps));
            const float is = 1.f/ssq;
            ccs[n][0] = (qrr*srr + qii*sii)*is;
            ccs[n][1] = (qii*srr - qrr*sii)*is;
        }
    }

    // ---- U as B-frag (hi/lo bf16), register-only; overlaps 0a stores ----
    s8 Uh, Ul;
    {
        const float uu[8] = {ua0.x,ua0.y,ua0.z,ua0.w, ua1.x,ua1.y,ua1.z,ua1.w};
#pragma unroll
        for (int j = 0; j < 8; ++j) {
            const unsigned short hv = f2bf(uu[j]);
            Uh[j] = (short)hv; Ul[j] = (short)f2bf(uu[j] - bf2f(hv));
        }
    }
    __syncthreads();                              // bar0: pre/pim/ccs ready

    // ---------- Stage A: S = Zf @ U ----------
    f4 Sre[2] = {{0.f,0.f,0.f,0.f},{0.f,0.f,0.f,0.f}};
    f4 Sim[2] = {{0.f,0.f,0.f,0.f},{0.f,0.f,0.f,0.f}};
#pragma unroll
    for (int mb = 0; mb < 2; ++mb) {
        const int n = cl + 16*mb;                 // A-row = mode
        s8 a0, a1, a2, a3;
#pragma unroll
        for (int j = 0; j < 8; ++j) {
            const int e = 31 - (8*hq + j);        // Zf[n][k] = z^{31-k}
            const float vr = pre[n][e], vi = pim[n][e];
            const unsigned short h1 = f2bf(vr);
            a0[j] = (short)h1; a1[j] = (short)f2bf(vr - bf2f(h1));
            const unsigned short h2 = f2bf(vi);
            a2[j] = (short)h2; a3[j] = (short)f2bf(vi - bf2f(h2));
        }
        Sre[mb] = MFMA(a0, Uh, Sre[mb], 0,0,0);
        Sre[mb] = MFMA(a0, Ul, Sre[mb], 0,0,0);
        Sre[mb] = MFMA(a1, Uh, Sre[mb], 0,0,0);
        Sim[mb] = MFMA(a2, Uh, Sim[mb], 0,0,0);
        Sim[mb] = MFMA(a2, Ul, Sim[mb], 0,0,0);
        Sim[mb] = MFMA(a3, Uh, Sim[mb], 0,0,0);
    }
#pragma unroll
    for (int mb = 0; mb < 2; ++mb)
#pragma unroll
        for (int r = 0; r < 4; ++r) {
            const int mode = 16*mb + 4*hq + r;    // D-row = mode
            *(float2*)&SL[c][2*mode] = make_float2(Sre[mb][r], Sim[mb][r]);
        }

    // ---------- 0b: K[e] (overlaps stage A MFMA drain) ----------
    {
        const int e = tid >> 3, g = tid & 7;
        float acc = 0.f;
#pragma unroll
        for (int t = 0; t < 4; ++t) {
            const int n = 4*g + t;
            acc = fmaf(ccs[n][0], pre[n][e], acc);
            acc = fmaf(-ccs[n][1], pim[n][e], acc);
        }
        acc += __shfl_down(acc, 4);
        acc += __shfl_down(acc, 2);
        acc += __shfl_down(acc, 1);
        if (g == 0) Kk[e] = acc;
    }
    __syncthreads();                              // bar1: S + Kk ready

    // ---------- Stage B: 64-chunk Kogge-Stone carry scan ----------
    float Xr[8], Xi[8];
#pragma unroll
    for (int q = 0; q < 8; ++q) {
        const float2 v = *(const float2*)&SL[lane][16*wv + 2*q];
        Xr[q] = v.x; Xi[q] = v.y;
    }
    __syncthreads();                              // bar2: all S reads drained
#pragma unroll
    for (int q = 0; q < 8; ++q) {
        const float vr = __shfl_up(Xr[q], 1), vi = __shfl_up(Xi[q], 1);
        Xr[q] = (lane >= 1) ? vr : 0.f;
        Xi[q] = (lane >= 1) ? vi : 0.f;
    }
    float prq[8], piq[8];
#pragma unroll
    for (int q = 0; q < 8; ++q) {                 // ratio z^32 (regs pinned)
        prq[q] = pre[8*wv + q][32];
        piq[q] = pim[8*wv + q][32];
        asm volatile("" : "+v"(prq[q]), "+v"(piq[q]));
    }
#pragma unroll 1
    for (int d = 1; d < 64; d <<= 1) {
#pragma unroll
        for (int q = 0; q < 8; ++q) {
            float vr = __shfl_up(Xr[q], d), vi = __shfl_up(Xi[q], d);
            const bool ok = lane >= d;
            vr = ok ? vr : 0.f; vi = ok ? vi : 0.f;
            Xr[q] = fmaf(prq[q], vr, fmaf(-piq[q], vi, Xr[q]));
            Xi[q] = fmaf(prq[q], vi, fmaf(piq[q], vr, Xi[q]));
        }
#pragma unroll
        for (int q = 0; q < 8; ++q) {
            const float t = fmaf(prq[q], prq[q], -piq[q]*piq[q]);
            piq[q] = 2.f*prq[q]*piq[q]; prq[q] = t;
        }
    }
    const int wvu = __builtin_amdgcn_readfirstlane(wv);
#pragma unroll
    for (int q = 0; q < 8; ++q) {                 // carries back into SL
        *(float2*)&SL[lane][16*wvu + 2*q] = make_float2(Xr[q], Xi[q]);
    }
    __syncthreads();                              // bar3: carries ready

    // ---------- Stage C: y = T@U + Rre@CarRe + Rni@CarIm ----------
    s8 Crh, Crl, Cih, Cil;
#pragma unroll
    for (int jj = 0; jj < 8; ++jj) {              // modes 8hq..8hq+7, chunk c
        const float2 cv = *(const float2*)&SL[c][16*hq + 2*jj];
        const unsigned short t1 = f2bf(cv.x);
        Crh[jj] = (short)t1; Crl[jj] = (short)f2bf(cv.x - bf2f(t1));
        const unsigned short t2 = f2bf(cv.y);
        Cih[jj] = (short)t2; Cil[jj] = (short)f2bf(cv.y - bf2f(t2));
    }
#pragma unroll
    for (int ib = 0; ib < 2; ++ib) {
        const int i = cl + 16*ib;                 // A-row = output elem
        s8 th_, tl_, r0, r1, r2, r3;
#pragma unroll
        for (int jj = 0; jj < 8; ++jj) {
            const int j = 8*hq + jj;              // A-col (k)
            const float kv = (j <= i) ? Kk[i - j] : 0.f;
            const unsigned short hv = f2bf(kv);
            th_[jj] = (short)hv; tl_[jj] = (short)f2bf(kv - bf2f(hv));
            const int m = j;                      // mode for R
            const float pr_ = pre[m][i+1], pi_ = pim[m][i+1];
            const float crm = ccs[m][0], cim = ccs[m][1];
            const float Rre = fmaf(crm, pr_, -cim*pi_);
            const float Rni = -fmaf(crm, pi_, cim*pr_);
            const unsigned short h1 = f2bf(Rre);
            r0[jj] = (short)h1; r1[jj] = (short)f2bf(Rre - bf2f(h1));
            const unsigned short h2 = f2bf(Rni);
            r2[jj] = (short)h2; r3[jj] = (short)f2bf(Rni - bf2f(h2));
        }
        f4 acc = {0.f,0.f,0.f,0.f};
        acc = MFMA(th_, Uh, acc, 0,0,0);
        acc = MFMA(th_, Ul, acc, 0,0,0);
        acc = MFMA(tl_, Uh, acc, 0,0,0);
        acc = MFMA(r0, Crh, acc, 0,0,0);
        acc = MFMA(r0, Crl, acc, 0,0,0);
        acc = MFMA(r1, Crh, acc, 0,0,0);
        acc = MFMA(r2, Cih, acc, 0,0,0);
        acc = MFMA(r2, Cil, acc, 0,0,0);
        acc = MFMA(r3, Cih, acc, 0,0,0);
#pragma unroll
        for (int r = 0; r < 4; ++r) {
            YL[c][16*ib + 4*hq + r] = acc[r];     // y-index i = 16ib+4hq+r
        }
    }
    __syncthreads();                              // bar4: YL ready

    // ---------- epilogue: y = D*u + YL, coalesced ----------
    const float Dh = Dv[h];
    float* yg = y + (size_t)h * kL;
    for (int e = tid; e < kL; e += 256) {
        yg[e] = fmaf(Dh, ug[e], YL[e >> 5][e & 31]);
    }
}

extern "C" void kernel_launch(void* const* d_in, const int* in_sizes, int n_in,
                              void* d_out, int out_size, void* d_ws, size_t ws_size,
                              hipStream_t stream) {
    const float* u        = (const float*)d_in[0];  // (H, L)
    const float* W        = (const float*)d_in[1];  // (H, N, 2)
    const float* Lam      = (const float*)d_in[2];  // (N, 2)
    const float* log_step = (const float*)d_in[3];  // (H,)
    const float* Dv       = (const float*)d_in[4];  // (H,)
    float* y = (float*)d_out;                       // (H, L) fp32

    dss_fused<<<kH, 256, 0, stream>>>(u, W, Lam, log_step, Dv, y);
}